// Round 8
// baseline (112.244 us; speedup 1.0000x reference)
//
#include <hip/hip_runtime.h>
#include <cstdint>
#include <cstddef>

#define NN 50000
#define FF 128
#define CC 128
#define KK 10

constexpr int TILES_P = NN / 16;            // 3125 row-tiles per protein
constexpr size_t NC = (size_t)NN * CC;      // 6.4M elements per protein
constexpr int GEMM_GRID  = 768;             // 3 blocks/CU exactly (LDS 48KB each)
constexpr int GEMM_TOTAL = 2 * (2 * TILES_P);   // 12500 (tile, col-half) items
constexpr int GEMM_ITERS = 17;              // 768*17 = 13056 >= 12500 (wrap = idempotent redo)

typedef __bf16 bf16x8 __attribute__((ext_vector_type(8)));
typedef float  f32x4  __attribute__((ext_vector_type(4)));
typedef float  f32x2  __attribute__((ext_vector_type(2)));
typedef unsigned u32x2 __attribute__((ext_vector_type(2)));

__device__ __forceinline__ unsigned f2bf_u(float f) {
  union { float f; unsigned u; } x; x.f = f;
  unsigned r = x.u + 0x7fffu + ((x.u >> 16) & 1u);   // RNE
  return r >> 16;
}

// ---------------------------------------------------------------------------
// Phase 1: S = Z@Wsv -> ws (bf16); Rs = Z@Wsr, Rd = Z@Wdr -> ws (e4m3, HW cvt).
// R7 post-mortem: LDS W-staging landed but dur unmoved -> the binding defect
// was the CONDITIONAL prefetch: memory ops inside `if (wi < total)` make
// outstanding-op counts unprovable, forcing conservative s_waitcnt vmcnt(0)
// at every loop top -> each iteration drains the just-issued scattered
// stores (~1-2k cy serial). Fix: fully straight-line steady-state loop:
//  * fixed 17 iterations for ALL 768 blocks; index wraps mod 12500, so the
//    556 pad tiles recompute tile 0..555 and store IDENTICAL bytes (benign).
//  * depth-2 ping-pong prefetch (preA/preB), manually unrolled x2 so buffer
//    choice is static; prefetch issued between convert and MFMA.
//  * no conditional memory ops anywhere -> compiler emits counted vmcnt(N);
//    stores retire in-order in the background, never drained.
// W frags stay in LDS (fragment-order, conflict-free b128); LDS 48KB also
// relaxes the regalloc occupancy target to 3 waves/SIMD (VGPR budget ~168).
// Operand-swap: acc = mfma(Wfrag, Zfrag) -> lane holds 4 consecutive cols of
// one node -> fp8 quad = one dword store, S = one dwordx2 store.
// ---------------------------------------------------------------------------
__global__ __launch_bounds__(256)
void gemm3_kernel(const float* __restrict__ Z1, const float* __restrict__ Z2,
                  const float* __restrict__ Wsv, const float* __restrict__ Wsr,
                  const float* __restrict__ Wdr,
                  unsigned short* __restrict__ tblS, unsigned char* __restrict__ tbl8)
{
  const int tid  = threadIdx.x;
  const int wave = tid >> 6;
  const int lane = tid & 63;
  const int l15  = lane & 15;
  const int lg   = lane >> 4;

  __shared__ __align__(16) unsigned short wlds[4 * 12 * 64 * 8];   // 48 KB

  const int bid  = blockIdx.x;             // 0..767; parity invariant under
  const int half = bid & 1;                // +768 and -12500 (both even)
  const int wcol = half * 64 + wave * 16;

  // ---- issue Z prefetch for it=0 / it=1 FIRST (hide under W staging) ----
  auto loads = [&](f32x4 (&pre)[8], int wi) {
    const int t    = wi >> 1;
    const int p    = (t >= TILES_P) ? 1 : 0;
    const int row0 = (t - p * TILES_P) * 16;
    const float* __restrict__ Z = p ? Z2 : Z1;
    const float* zrow = Z + (size_t)(row0 + l15) * FF;
#pragma unroll
    for (int s = 0; s < 4; ++s) {
      pre[s]     = *(const f32x4*)(zrow + s * 32 + lg * 4);
      pre[4 + s] = *(const f32x4*)(zrow + s * 32 + 16 + lg * 4);
    }
  };

  int wiC = bid;                 // tile for current step
  int wiN = bid + GEMM_GRID;     // tile for next step        (< 12500 always)
  int wpf = bid + 2 * GEMM_GRID; // tile to prefetch          (< 12500 always)

  f32x4 preA[8], preB[8];
  loads(preA, wiC);
  loads(preB, wiN);

  // ---- stage W slice into LDS as per-lane MFMA frags (once per block) ----
  {
    const float* Wm[3] = { Wsv, Wsr, Wdr };
#pragma unroll
    for (int m = 0; m < 3; ++m) {
      const float* __restrict__ W = Wm[m];
      const int col = wcol + l15;
#pragma unroll
      for (int s = 0; s < 4; ++s) {
        bf16x8 f;
#pragma unroll
        for (int e = 0; e < 8; ++e) {
          const int k = s * 32 + (e >> 2) * 16 + lg * 4 + (e & 3);
          f[e] = (__bf16)W[k * CC + col];
        }
        *(bf16x8*)&wlds[((wave * 12 + m * 4 + s) * 64 + lane) * 8] = f;
      }
    }
  }
  __syncthreads();

  auto conv = [&](const f32x4 (&pre)[8], bf16x8 (&a)[4]) {
#pragma unroll
    for (int s = 0; s < 4; ++s) {
      const f32x4 ha = pre[s];
      const f32x4 hb = pre[4 + s];
      bf16x8 f;
      f[0] = (__bf16)ha.x; f[1] = (__bf16)ha.y; f[2] = (__bf16)ha.z; f[3] = (__bf16)ha.w;
      f[4] = (__bf16)hb.x; f[5] = (__bf16)hb.y; f[6] = (__bf16)hb.z; f[7] = (__bf16)hb.w;
      a[s] = f;
    }
  };

  auto work = [&](const bf16x8 (&a)[4], int wi) {
    f32x4 acc[3] = {};
#pragma unroll
    for (int s = 0; s < 4; ++s)
#pragma unroll
      for (int m = 0; m < 3; ++m) {
        const bf16x8 bfrag = *(const bf16x8*)&wlds[((wave * 12 + m * 4 + s) * 64 + lane) * 8];
        acc[m] = __builtin_amdgcn_mfma_f32_16x16x32_bf16(bfrag, a[s], acc[m], 0, 0, 0);
      }
    const int t    = wi >> 1;
    const int p    = (t >= TILES_P) ? 1 : 0;
    const int row0 = (t - p * TILES_P) * 16;
    const int node = row0 + l15;
    const int cb   = wcol + lg * 4;
    const size_t o = (size_t)node * CC + cb;
    unsigned short* tS  = tblS + (size_t)p * NC;
    unsigned char*  tRs = tbl8 + (size_t)(2 * p + 0) * NC;
    unsigned char*  tRd = tbl8 + (size_t)(2 * p + 1) * NC;

    u32x2 sv;
    sv.x = f2bf_u(acc[0][0]) | (f2bf_u(acc[0][1]) << 16);
    sv.y = f2bf_u(acc[0][2]) | (f2bf_u(acc[0][3]) << 16);
    *(u32x2*)(tS + o) = sv;

    int pk = __builtin_amdgcn_cvt_pk_fp8_f32(acc[1][0], acc[1][1], 0, false);
    pk     = __builtin_amdgcn_cvt_pk_fp8_f32(acc[1][2], acc[1][3], pk, true);
    *(unsigned*)(tRs + o) = (unsigned)pk;

    pk = __builtin_amdgcn_cvt_pk_fp8_f32(acc[2][0], acc[2][1], 0, false);
    pk = __builtin_amdgcn_cvt_pk_fp8_f32(acc[2][2], acc[2][3], pk, true);
    *(unsigned*)(tRd + o) = (unsigned)pk;
  };

  auto adv = [](int w) {                 // uniform select, no branch
    w += GEMM_GRID;
    return (w >= GEMM_TOTAL) ? (w - GEMM_TOTAL) : w;
  };

  // 16 steady-state steps (8 x unroll-2), all memory ops unconditional
#pragma unroll 1
  for (int k = 0; k < 8; ++k) {
    {
      bf16x8 a[4];
      conv(preA, a);
      loads(preA, wpf);          // depth-2 prefetch into just-freed buffer
      work(a, wiC);
      wiC = wiN; wiN = wpf; wpf = adv(wpf);
    }
    {
      bf16x8 a[4];
      conv(preB, a);
      loads(preB, wpf);
      work(a, wiC);
      wiC = wiN; wiN = wpf; wpf = adv(wpf);
    }
  }
  // tail: iteration 17 (preA), no prefetch — still straight-line
  {
    bf16x8 a[4];
    conv(preA, a);
    work(a, wiC);
  }
}

// ---------------------------------------------------------------------------
// Phase 2: one wave per node, lane covers 2 cols (ushort = 2 x e4m3).
// Node id in SGPR -> scalar index loads; 20 gathers issued as one batch;
// the asm memory barrier FORCES all loads before any use (keeps MLP).
// Decode via HW v_cvt_pk_f32_fp8 (1 instr -> 2 floats).
// ---------------------------------------------------------------------------
__global__ __launch_bounds__(256)
void agg_kernel(const int* __restrict__ same1, const int* __restrict__ diff1,
                const int* __restrict__ same2, const int* __restrict__ diff2,
                const unsigned short* __restrict__ tblS,
                const unsigned char* __restrict__ tbl8,
                float* __restrict__ out)
{
  const int lane = threadIdx.x & 63;
  const int g    = __builtin_amdgcn_readfirstlane(blockIdx.x * 4 + (threadIdx.x >> 6));
  const int p    = (g >= NN) ? 1 : 0;
  const int node = g - p * NN;
  const int* __restrict__ same = p ? same2 : same1;
  const int* __restrict__ diff = p ? diff2 : diff1;
  const unsigned char* __restrict__ tRs = tbl8 + (size_t)(2 * p + 0) * NC;
  const unsigned char* __restrict__ tRd = tbl8 + (size_t)(2 * p + 1) * NC;

  int idx[2 * KK];
#pragma unroll
  for (int k = 0; k < KK; ++k) {
    idx[k]      = same[node * KK + k];
    idx[KK + k] = diff[node * KK + k];
  }

  unsigned val[2 * KK];
#pragma unroll
  for (int i = 0; i < 2 * KK; ++i) {
    const unsigned char* __restrict__ t = (i < KK) ? tRs : tRd;
    const int ic = idx[i] < 0 ? 0 : idx[i];
    val[i] = *(const unsigned short*)(t + (size_t)ic * CC + lane * 2);
  }
  const size_t o = (size_t)g * CC + (size_t)(lane * 2);
  const unsigned su = *(const unsigned*)(tblS + o);

  asm volatile("" ::: "memory");   // keep all 20 gathers + S load in flight

  float s0 = 0.f, s1 = 0.f, d0 = 0.f, d1 = 0.f;
  int sc = 0, dc = 0;
#pragma unroll
  for (int i = 0; i < KK; ++i) {
    sc += (idx[i] >= 0);
    const unsigned u = (idx[i] >= 0) ? val[i] : 0u;
    f32x2 pr = __builtin_amdgcn_cvt_pk_f32_fp8(u, false);
    s0 += pr.x; s1 += pr.y;
  }
#pragma unroll
  for (int i = KK; i < 2 * KK; ++i) {
    dc += (idx[i] >= 0);
    const unsigned u = (idx[i] >= 0) ? val[i] : 0u;
    f32x2 pr = __builtin_amdgcn_cvt_pk_f32_fp8(u, false);
    d0 += pr.x; d1 += pr.y;
  }

  union { unsigned u; float f; } slo, shi;
  slo.u = su << 16;
  shi.u = su & 0xFFFF0000u;

  const float fs = 1.f / (float)(sc > 0 ? sc : 1);
  const float fd = 1.f / (float)(dc > 0 ? dc : 1);
  const float vlo = slo.f + s0 * fs + d0 * fd;
  const float vhi = shi.f + s1 * fs + d1 * fd;
  f32x2 r;
  r.x = vlo > 0.f ? vlo : 0.f;
  r.y = vhi > 0.f ? vhi : 0.f;
  __builtin_nontemporal_store(r, (f32x2*)(out + o));
}

// ---------------------------------------------------------------------------
// Safety fallback if ws is too small: direct per-node recompute (slow, correct).
// ---------------------------------------------------------------------------
__global__ __launch_bounds__(128)
void fallback_kernel(const float* __restrict__ Z, const int* __restrict__ same,
                     const int* __restrict__ diff,
                     const float* __restrict__ Wsv, const float* __restrict__ Wsr,
                     const float* __restrict__ Wdr, float* __restrict__ out)
{
  const int node = blockIdx.x;
  const int c    = threadIdx.x;
  __shared__ float zs[FF];
  zs[c] = Z[(size_t)node * FF + c];
  __syncthreads();
  float sig = 0.f;
  for (int f = 0; f < FF; ++f) sig += zs[f] * Wsv[f * CC + c];

  float ssum = 0.f, dsum = 0.f;
  int scnt = 0, dcnt = 0;
  for (int k = 0; k < KK; ++k) {
    const int is = same[node * KK + k];
    if (is >= 0) {
      __syncthreads();
      zs[c] = Z[(size_t)is * FF + c];
      __syncthreads();
      float a = 0.f;
      for (int f = 0; f < FF; ++f) a += zs[f] * Wsr[f * CC + c];
      ssum += a; scnt++;
    }
  }
  for (int k = 0; k < KK; ++k) {
    const int id = diff[node * KK + k];
    if (id >= 0) {
      __syncthreads();
      zs[c] = Z[(size_t)id * FF + c];
      __syncthreads();
      float a = 0.f;
      for (int f = 0; f < FF; ++f) a += zs[f] * Wdr[f * CC + c];
      dsum += a; dcnt++;
    }
  }
  const float v = sig + ssum / (float)(scnt > 0 ? scnt : 1)
                      + dsum / (float)(dcnt > 0 ? dcnt : 1);
  out[(size_t)node * CC + c] = v > 0.f ? v : 0.f;
}

extern "C" void kernel_launch(void* const* d_in, const int* in_sizes, int n_in,
                              void* d_out, int out_size, void* d_ws, size_t ws_size,
                              hipStream_t stream)
{
  const float* Z1    = (const float*)d_in[0];
  const int*   same1 = (const int*)  d_in[1];
  const int*   diff1 = (const int*)  d_in[2];
  const float* Z2    = (const float*)d_in[3];
  const int*   same2 = (const int*)  d_in[4];
  const int*   diff2 = (const int*)  d_in[5];
  const float* Wsv   = (const float*)d_in[6];
  const float* Wsr   = (const float*)d_in[7];
  const float* Wdr   = (const float*)d_in[8];
  float* out = (float*)d_out;

  // ws layout: [ S bf16: 2*NC ushort | tables e4m3: 4*NC bytes ] = 8*NC bytes
  const size_t need = 8 * NC;
  unsigned short* tblS = (unsigned short*)d_ws;
  unsigned char*  tbl8 = (unsigned char*)d_ws + 2 * NC * sizeof(unsigned short);

  if (ws_size >= need) {
    gemm3_kernel<<<GEMM_GRID, 256, 0, stream>>>(Z1, Z2, Wsv, Wsr, Wdr, tblS, tbl8);
    agg_kernel<<<(2 * NN) / 4, 256, 0, stream>>>(same1, diff1, same2, diff2,
                                                 tblS, tbl8, out);
  } else {
    fallback_kernel<<<NN, 128, 0, stream>>>(Z1, same1, diff1, Wsv, Wsr, Wdr, out);
    fallback_kernel<<<NN, 128, 0, stream>>>(Z2, same2, diff2, Wsv, Wsr, Wdr, out + NC);
  }
}

// Round 9
// 84.818 us; speedup vs baseline: 1.3233x; 1.3233x over previous
//
#include <hip/hip_runtime.h>
#include <cstdint>
#include <cstddef>

#define NN 50000
#define FF 128
#define CC 128
#define KK 10

constexpr int TILES_P = NN / 16;            // 3125 row-tiles per protein
constexpr size_t NC = (size_t)NN * CC;      // 6.4M elements per protein

typedef __bf16 bf16x8 __attribute__((ext_vector_type(8)));
typedef float  f32x4  __attribute__((ext_vector_type(4)));
typedef float  f32x2  __attribute__((ext_vector_type(2)));

__device__ __forceinline__ unsigned f2bf_u(float f) {
  union { float f; unsigned u; } x; x.f = f;
  unsigned r = x.u + 0x7fffu + ((x.u >> 16) & 1u);   // RNE
  return r >> 16;
}

// ---------------------------------------------------------------------------
// Phase 1: S = Z@Wsv -> ws (bf16); Rs = Z@Wsr, Rd = Z@Wdr -> ws (e4m3, HW cvt).
// R8 post-mortem: every post-R2 structural rewrite (reg pin, LDS W-staging,
// straight-line pipeline) landed per-counters yet gemm stayed 61-78 µs, while
// R2's naive loop ran 38 µs. The variable tracking the regression is STORE
// SEGMENT WIDTH: R2 wrote 16 consecutive lanes -> 16 consecutive columns
// (32-64B contiguous segments); the R4+ operand-swap layout wrote scattered
// 8-16B segments (partial-sector writes -> L2 transaction storm).
// R9 = R2 structure verbatim (non-swapped mfma(a,b), b[3][2][4] register
// frags, no pin/LDS/prefetch, launch_bounds(256,2), grid 512, plain
// grid-stride loop) with ONE change: B-column mapping col0+2*l15+j instead of
// col0+j*16+l15, so a lane's two j-accs are ADJACENT columns of the same row:
//   S packs 2 bf16 -> 1 dword store  (16 lanes x 4B = 64B segments)
//   Rs/Rd pack 2 fp8 -> 1 ushort store (16 lanes x 2B = 32B segments)
// All stores >=32B contiguous, half the store instrs of R2.
// ---------------------------------------------------------------------------
__global__ __launch_bounds__(256, 2)
void gemm3_kernel(const float* __restrict__ Z1, const float* __restrict__ Z2,
                  const float* __restrict__ Wsv, const float* __restrict__ Wsr,
                  const float* __restrict__ Wdr,
                  unsigned short* __restrict__ tblS, unsigned char* __restrict__ tbl8)
{
  const int tid  = threadIdx.x;
  const int wave = tid >> 6;
  const int lane = tid & 63;
  const int l15  = lane & 15;
  const int lg   = lane >> 4;
  const int col0 = wave * 32;

  // ---- W frags in registers: col = col0 + 2*l15 + j (adjacent j-pair) ----
  const float* Wm[3] = { Wsv, Wsr, Wdr };
  bf16x8 b[3][2][4];
#pragma unroll
  for (int m = 0; m < 3; ++m) {
    const float* __restrict__ W = Wm[m];
#pragma unroll
    for (int j = 0; j < 2; ++j) {
      const int col = col0 + 2 * l15 + j;
#pragma unroll
      for (int s = 0; s < 4; ++s) {
        bf16x8 f;
#pragma unroll
        for (int e = 0; e < 8; ++e) {
          const int k = s * 32 + (e >> 2) * 16 + lg * 4 + (e & 3);
          f[e] = (__bf16)W[k * CC + col];
        }
        b[m][j][s] = f;
      }
    }
  }

  const int total = 2 * TILES_P;
  for (int t = blockIdx.x; t < total; t += gridDim.x) {
    const int p    = (t >= TILES_P) ? 1 : 0;
    const int row0 = (t - p * TILES_P) * 16;
    const float* __restrict__ Z = p ? Z2 : Z1;
    const float* zrow = Z + (size_t)(row0 + l15) * FF;

    bf16x8 a[4];
#pragma unroll
    for (int s = 0; s < 4; ++s) {
      const f32x4 ha = *(const f32x4*)(zrow + s * 32 + lg * 4);
      const f32x4 hb = *(const f32x4*)(zrow + s * 32 + 16 + lg * 4);
      bf16x8 f;
      f[0] = (__bf16)ha.x; f[1] = (__bf16)ha.y; f[2] = (__bf16)ha.z; f[3] = (__bf16)ha.w;
      f[4] = (__bf16)hb.x; f[5] = (__bf16)hb.y; f[6] = (__bf16)hb.z; f[7] = (__bf16)hb.w;
      a[s] = f;
    }

    f32x4 acc[3][2] = {};
#pragma unroll
    for (int s = 0; s < 4; ++s)
#pragma unroll
      for (int m = 0; m < 3; ++m)
#pragma unroll
        for (int j = 0; j < 2; ++j)
          acc[m][j] = __builtin_amdgcn_mfma_f32_16x16x32_bf16(a[s], b[m][j][s], acc[m][j], 0, 0, 0);

    unsigned short* tS  = tblS + (size_t)p * NC;
    unsigned char*  tRs = tbl8 + (size_t)(2 * p + 0) * NC;
    unsigned char*  tRd = tbl8 + (size_t)(2 * p + 1) * NC;
#pragma unroll
    for (int r = 0; r < 4; ++r) {
      const int row = row0 + lg * 4 + r;
      const size_t o = (size_t)row * CC + col0 + 2 * l15;   // cols 2*l15, 2*l15+1

      *(unsigned*)(tS + o) = f2bf_u(acc[0][0][r]) | (f2bf_u(acc[0][1][r]) << 16);

      const int pks = __builtin_amdgcn_cvt_pk_fp8_f32(acc[1][0][r], acc[1][1][r], 0, false);
      *(unsigned short*)(tRs + o) = (unsigned short)pks;

      const int pkd = __builtin_amdgcn_cvt_pk_fp8_f32(acc[2][0][r], acc[2][1][r], 0, false);
      *(unsigned short*)(tRd + o) = (unsigned short)pkd;
    }
  }
}

// ---------------------------------------------------------------------------
// Phase 2: one wave per node, lane covers 2 cols (ushort = 2 x e4m3).
// Node id in SGPR -> scalar index loads; 20 gathers issued as one batch;
// the asm memory barrier FORCES all loads before any use (keeps MLP).
// Decode via HW v_cvt_pk_f32_fp8 (1 instr -> 2 floats).
// ---------------------------------------------------------------------------
__global__ __launch_bounds__(256)
void agg_kernel(const int* __restrict__ same1, const int* __restrict__ diff1,
                const int* __restrict__ same2, const int* __restrict__ diff2,
                const unsigned short* __restrict__ tblS,
                const unsigned char* __restrict__ tbl8,
                float* __restrict__ out)
{
  const int lane = threadIdx.x & 63;
  const int g    = __builtin_amdgcn_readfirstlane(blockIdx.x * 4 + (threadIdx.x >> 6));
  const int p    = (g >= NN) ? 1 : 0;
  const int node = g - p * NN;
  const int* __restrict__ same = p ? same2 : same1;
  const int* __restrict__ diff = p ? diff2 : diff1;
  const unsigned char* __restrict__ tRs = tbl8 + (size_t)(2 * p + 0) * NC;
  const unsigned char* __restrict__ tRd = tbl8 + (size_t)(2 * p + 1) * NC;

  int idx[2 * KK];
#pragma unroll
  for (int k = 0; k < KK; ++k) {
    idx[k]      = same[node * KK + k];
    idx[KK + k] = diff[node * KK + k];
  }

  unsigned val[2 * KK];
#pragma unroll
  for (int i = 0; i < 2 * KK; ++i) {
    const unsigned char* __restrict__ t = (i < KK) ? tRs : tRd;
    const int ic = idx[i] < 0 ? 0 : idx[i];
    val[i] = *(const unsigned short*)(t + (size_t)ic * CC + lane * 2);
  }
  const size_t o = (size_t)g * CC + (size_t)(lane * 2);
  const unsigned su = *(const unsigned*)(tblS + o);

  asm volatile("" ::: "memory");   // keep all 20 gathers + S load in flight

  float s0 = 0.f, s1 = 0.f, d0 = 0.f, d1 = 0.f;
  int sc = 0, dc = 0;
#pragma unroll
  for (int i = 0; i < KK; ++i) {
    sc += (idx[i] >= 0);
    const unsigned u = (idx[i] >= 0) ? val[i] : 0u;
    f32x2 pr = __builtin_amdgcn_cvt_pk_f32_fp8(u, false);
    s0 += pr.x; s1 += pr.y;
  }
#pragma unroll
  for (int i = KK; i < 2 * KK; ++i) {
    dc += (idx[i] >= 0);
    const unsigned u = (idx[i] >= 0) ? val[i] : 0u;
    f32x2 pr = __builtin_amdgcn_cvt_pk_f32_fp8(u, false);
    d0 += pr.x; d1 += pr.y;
  }

  union { unsigned u; float f; } slo, shi;
  slo.u = su << 16;
  shi.u = su & 0xFFFF0000u;

  const float fs = 1.f / (float)(sc > 0 ? sc : 1);
  const float fd = 1.f / (float)(dc > 0 ? dc : 1);
  const float vlo = slo.f + s0 * fs + d0 * fd;
  const float vhi = shi.f + s1 * fs + d1 * fd;
  f32x2 r;
  r.x = vlo > 0.f ? vlo : 0.f;
  r.y = vhi > 0.f ? vhi : 0.f;
  __builtin_nontemporal_store(r, (f32x2*)(out + o));
}

// ---------------------------------------------------------------------------
// Safety fallback if ws is too small: direct per-node recompute (slow, correct).
// ---------------------------------------------------------------------------
__global__ __launch_bounds__(128)
void fallback_kernel(const float* __restrict__ Z, const int* __restrict__ same,
                     const int* __restrict__ diff,
                     const float* __restrict__ Wsv, const float* __restrict__ Wsr,
                     const float* __restrict__ Wdr, float* __restrict__ out)
{
  const int node = blockIdx.x;
  const int c    = threadIdx.x;
  __shared__ float zs[FF];
  zs[c] = Z[(size_t)node * FF + c];
  __syncthreads();
  float sig = 0.f;
  for (int f = 0; f < FF; ++f) sig += zs[f] * Wsv[f * CC + c];

  float ssum = 0.f, dsum = 0.f;
  int scnt = 0, dcnt = 0;
  for (int k = 0; k < KK; ++k) {
    const int is = same[node * KK + k];
    if (is >= 0) {
      __syncthreads();
      zs[c] = Z[(size_t)is * FF + c];
      __syncthreads();
      float a = 0.f;
      for (int f = 0; f < FF; ++f) a += zs[f] * Wsr[f * CC + c];
      ssum += a; scnt++;
    }
  }
  for (int k = 0; k < KK; ++k) {
    const int id = diff[node * KK + k];
    if (id >= 0) {
      __syncthreads();
      zs[c] = Z[(size_t)id * FF + c];
      __syncthreads();
      float a = 0.f;
      for (int f = 0; f < FF; ++f) a += zs[f] * Wdr[f * CC + c];
      dsum += a; dcnt++;
    }
  }
  const float v = sig + ssum / (float)(scnt > 0 ? scnt : 1)
                      + dsum / (float)(dcnt > 0 ? dcnt : 1);
  out[(size_t)node * CC + c] = v > 0.f ? v : 0.f;
}

extern "C" void kernel_launch(void* const* d_in, const int* in_sizes, int n_in,
                              void* d_out, int out_size, void* d_ws, size_t ws_size,
                              hipStream_t stream)
{
  const float* Z1    = (const float*)d_in[0];
  const int*   same1 = (const int*)  d_in[1];
  const int*   diff1 = (const int*)  d_in[2];
  const float* Z2    = (const float*)d_in[3];
  const int*   same2 = (const int*)  d_in[4];
  const int*   diff2 = (const int*)  d_in[5];
  const float* Wsv   = (const float*)d_in[6];
  const float* Wsr   = (const float*)d_in[7];
  const float* Wdr   = (const float*)d_in[8];
  float* out = (float*)d_out;

  // ws layout: [ S bf16: 2*NC ushort | tables e4m3: 4*NC bytes ] = 8*NC bytes
  const size_t need = 8 * NC;
  unsigned short* tblS = (unsigned short*)d_ws;
  unsigned char*  tbl8 = (unsigned char*)d_ws + 2 * NC * sizeof(unsigned short);

  if (ws_size >= need) {
    gemm3_kernel<<<512, 256, 0, stream>>>(Z1, Z2, Wsv, Wsr, Wdr, tblS, tbl8);
    agg_kernel<<<(2 * NN) / 4, 256, 0, stream>>>(same1, diff1, same2, diff2,
                                                 tblS, tbl8, out);
  } else {
    fallback_kernel<<<NN, 128, 0, stream>>>(Z1, same1, diff1, Wsv, Wsr, Wdr, out);
    fallback_kernel<<<NN, 128, 0, stream>>>(Z2, same2, diff2, Wsv, Wsr, Wdr, out + NC);
  }
}